// Round 2
// baseline (87.385 us; speedup 1.0000x reference)
//
#include <hip/hip_runtime.h>

// Problem constants (from reference): B=8, N=1024, C=768, H=12, D=64
// Algebraic collapse: v is constant over the sequence dim, softmax rows sum
// to 1, so attention output == v == spe_agg broadcast. Final result:
//   out[b,n,:] = spe_agg[b,:] @ W_proj.T + b_proj   (independent of n and x)
#define BB 8
#define NN 1024
#define CC 768

// Kernel A: r[b,c] = dot(spe[b,:], Wp[c,:]) + bp[c]   (fp32)
// One wave (64 lanes) per output element; 6144 outputs.
__global__ __launch_bounds__(256) void proj_gemv_kernel(
    const float* __restrict__ spe,   // (B, C)
    const float* __restrict__ Wp,    // (C, C) row-major: Wp[c*C + c']
    const float* __restrict__ bp,    // (C,)
    float* __restrict__ r)           // (B, C) out
{
    const int wave = (blockIdx.x * blockDim.x + threadIdx.x) >> 6;
    const int lane = threadIdx.x & 63;
    const int b = wave / CC;
    const int c = wave - b * CC;

    const float* wrow = Wp + (size_t)c * CC;
    const float* srow = spe + (size_t)b * CC;

    float acc = 0.0f;
#pragma unroll
    for (int j = 0; j < 3; ++j) {
        const int base = (j * 64 + lane) * 4;   // float4 per lane, coalesced 16B
        float4 w4 = *reinterpret_cast<const float4*>(wrow + base);
        float4 s4 = *reinterpret_cast<const float4*>(srow + base);
        acc = fmaf(w4.x, s4.x, acc);
        acc = fmaf(w4.y, s4.y, acc);
        acc = fmaf(w4.z, s4.z, acc);
        acc = fmaf(w4.w, s4.w, acc);
    }
    // wave-64 butterfly reduction
#pragma unroll
    for (int off = 32; off > 0; off >>= 1)
        acc += __shfl_down(acc, off, 64);

    if (lane == 0) {
        r[b * CC + c] = acc + bp[c];
    }
}

// Kernel B: out[b,n,:] = r[b,:] for all n. float4 (16B) stores.
// i indexes float4 units; total B*N*C/4 = 1,572,864 units.
__global__ __launch_bounds__(256) void bcast_kernel(
    const float4* __restrict__ r,   // (B, C/4)
    float4* __restrict__ out)       // (B*N, C/4)
{
    const int i = blockIdx.x * blockDim.x + threadIdx.x;
    const int row = i / (CC / 4);          // b*N + n
    const int c4  = i - row * (CC / 4);
    const int b   = row >> 10;             // row / N, N=1024
    out[i] = r[b * (CC / 4) + c4];
}

extern "C" void kernel_launch(void* const* d_in, const int* in_sizes, int n_in,
                              void* d_out, int out_size, void* d_ws, size_t ws_size,
                              hipStream_t stream) {
    // inputs (fp32): 0=x (unused), 1=spe_agg (B,C), 2=W_qkv (unused),
    //                3=W_proj (C,C), 4=b_proj (C,)
    const float* spe = (const float*)d_in[1];
    const float* Wp  = (const float*)d_in[3];
    const float* bp  = (const float*)d_in[4];
    float* r = (float*)d_ws;   // B*C fp32 = 24 KiB scratch

    // Kernel A: 6144 waves = 1536 blocks of 256 (4 waves/block)
    proj_gemv_kernel<<<dim3((BB * CC) / 4), dim3(256), 0, stream>>>(spe, Wp, bp, r);

    // Kernel B: 1,572,864 float4 stores = 6144 blocks of 256
    bcast_kernel<<<dim3((BB * NN * CC / 4) / 256), dim3(256), 0, stream>>>(
        (const float4*)r, (float4*)d_out);
}